// Round 1
// baseline (270.426 us; speedup 1.0000x reference)
//
#include <hip/hip_runtime.h>
#include <math.h>

// Fused AntiAliasActivation: up2 (12-tap polyphase) -> snake -> down2 (12-tap)
// x: (B=16, C=512, T=4096) fp32, out: same shape.
//
// R4: fully register-blocked, LDS-free. One block per row; each thread
// computes W=16 contiguous outputs from its own x window held in regs.
//
// Phase-plane formulation (unchanged from R3):
//   E[s] = act( 2*sum_m x[clamp(s-3+m)]*u[11-2m] )   (yact[2s])
//   O[s] = act( 2*sum_m x[clamp(s-2+m)]*u[10-2m] )   (yact[2s+1])
//   out[o] = sum_m E[o-2+m]*d[2m+1] + sum_m O[o-3+m]*d[2m]
//   act(y) = y + rb*sin(y*ea)^2
// Down-conv pad clamp (t<0 -> E[0]; t>2T-1 -> O[T-1]) is thread-local:
// thread 0 owns E[-2..], thread 255 owns E/O[>=T].
//
// R4 vs R3 (89us kernel): R3 spent ~65% of per-block cycles in the LDS
// pipe (48 b128 ops/block + 560 conflict-cycles/block, 3 barriers).
// Per-thread windows make all of that register math: +30% activation
// redundancy (21 E + 21 O for 16 outputs) buys 0 LDS, 0 barriers.
// Filter prescale by 2.0f is exact -> numerics identical to R3.

#define T_LEN 4096
#define NT    256
#define W     16                 // outputs per thread; NT*W == T_LEN

__global__ __launch_bounds__(NT) void aa_act_kernel(
    const float* __restrict__ x,
    const float* __restrict__ alpha,
    const float* __restrict__ beta,
    const float* __restrict__ upf,
    const float* __restrict__ downf,
    float* __restrict__ out,
    int C)
{
    const int t   = threadIdx.x;
    const int row = blockIdx.x;
    const int c   = row % C;
    const int o0  = t * W;

    const float* __restrict__ xr = x + (size_t)row * T_LEN;
    float* __restrict__ outr     = out + (size_t)row * T_LEN;

    // Uniform filter taps. Prescale up-filter by 2 (UP factor) — exact.
    float ue[6], uo[6], d[12];
#pragma unroll
    for (int m = 0; m < 6; ++m) {
        ue[m] = 2.0f * upf[11 - 2 * m];
        uo[m] = 2.0f * upf[10 - 2 * m];
    }
#pragma unroll
    for (int i = 0; i < 12; ++i) d[i] = downf[i];

    const float ea = __expf(alpha[c]);
    const float rb = 1.0f / (__expf(beta[c]) + 1e-9f);

    // ---- x[o0-8 .. o0+23] -> f[0..31] (16B-aligned float4 loads) ----
    float f[32];
    if (t != 0 && t != NT - 1) {
        const float4* p = (const float4*)(xr + o0 - 8);
#pragma unroll
        for (int i = 0; i < 8; ++i) ((float4*)f)[i] = p[i];
    } else {
        // row-edge threads: scalar clamped loads (up-conv edge pad)
#pragma unroll
        for (int i = 0; i < 32; ++i)
            f[i] = xr[min(max(o0 - 8 + i, 0), T_LEN - 1)];
    }

    // ---- activations: e[i] = E[o0-2+i], o_[i] = O[o0-3+i], i=0..20 ----
    // Both use window x[o0-5+i .. o0+i] = f[i+3 .. i+8].
    float e[21], o_[21];
#pragma unroll
    for (int i = 0; i < 21; ++i) {
        float ye = f[i + 3] * ue[0];
        ye = fmaf(f[i + 4], ue[1], ye);
        ye = fmaf(f[i + 5], ue[2], ye);
        ye = fmaf(f[i + 6], ue[3], ye);
        ye = fmaf(f[i + 7], ue[4], ye);
        ye = fmaf(f[i + 8], ue[5], ye);
        float yo = f[i + 3] * uo[0];
        yo = fmaf(f[i + 4], uo[1], yo);
        yo = fmaf(f[i + 5], uo[2], yo);
        yo = fmaf(f[i + 6], uo[3], yo);
        yo = fmaf(f[i + 7], uo[4], yo);
        yo = fmaf(f[i + 8], uo[5], yo);
        float se = __sinf(ye * ea);
        float so = __sinf(yo * ea);
        e[i]  = fmaf(rb * se, se, ye);
        o_[i] = fmaf(rb * so, so, yo);
    }

    // ---- down-conv pad clamp fixups (thread-local at row edges) ----
    if (t == 0) {
        float L = e[2];                 // E[0]
        e[0] = L; e[1] = L;             // E[-2],E[-1]
        o_[0] = L; o_[1] = L; o_[2] = L;// O[-3..-1] -> yact[0] = E[0]
    }
    if (t == NT - 1) {
        float R = o_[18];               // O[T-1]
        e[18] = R; e[19] = R; e[20] = R;// E[T..T+2] -> yact[2T-1]
        o_[19] = R; o_[20] = R;         // O[T..T+1] -> yact[2T-1]
    }

    // ---- dual 6-tap down-conv: out[o0+r] ----
    float acc[W];
#pragma unroll
    for (int r = 0; r < W; ++r) {
        float a = e[r] * d[1];
        a = fmaf(e[r + 1], d[3],  a);
        a = fmaf(e[r + 2], d[5],  a);
        a = fmaf(e[r + 3], d[7],  a);
        a = fmaf(e[r + 4], d[9],  a);
        a = fmaf(e[r + 5], d[11], a);
        a = fmaf(o_[r],     d[0],  a);
        a = fmaf(o_[r + 1], d[2],  a);
        a = fmaf(o_[r + 2], d[4],  a);
        a = fmaf(o_[r + 3], d[6],  a);
        a = fmaf(o_[r + 4], d[8],  a);
        a = fmaf(o_[r + 5], d[10], a);
        acc[r] = a;
    }

#pragma unroll
    for (int i = 0; i < 4; ++i)
        ((float4*)(outr + o0))[i] = *(float4*)(acc + 4 * i);
}

extern "C" void kernel_launch(void* const* d_in, const int* in_sizes, int n_in,
                              void* d_out, int out_size, void* d_ws, size_t ws_size,
                              hipStream_t stream) {
    const float* x     = (const float*)d_in[0];
    const float* alpha = (const float*)d_in[1];
    const float* beta  = (const float*)d_in[2];
    const float* upf   = (const float*)d_in[3];
    const float* downf = (const float*)d_in[4];
    float* out = (float*)d_out;

    const int C    = in_sizes[1];             // 512
    const int rows = in_sizes[0] / T_LEN;     // B*C = 8192

    dim3 grid(rows), block(NT);
    hipLaunchKernelGGL(aa_act_kernel, grid, block, 0, stream,
                       x, alpha, beta, upf, downf, out, C);
}